// Round 1
// baseline (947.150 us; speedup 1.0000x reference)
//
#include <hip/hip_runtime.h>
#include <cstddef>

// SkipGRU on MI355X (gfx950).
// B=128, T=512, C=512, H=512, PT=16, SKIP=32 -> N=4096 sequences of length 16.
//
// Per step t: [s_t | h] (4096x1024) @ [[W],[U]] (1024x1536) fused with GRU gates.
// s_t rows: n=b*32+s -> x row (n>>5)*512 + t*32 + (n&31)  (32-row contiguous blocks).
// Gate 2 (hh) needs xh and rh separate (hh = relu(xh + r*rh)), so it gets two
// accumulators split across the two K-halves; z,r use one accumulator each.
//
// d_ws layout: Bp bf16[1536][1024] (3 MB) | h0 bf16[4096][512] | h1 (4 MB each).

typedef unsigned short u16;
typedef __attribute__((ext_vector_type(8))) short short8;
typedef __attribute__((ext_vector_type(8))) u16 u16x8;
typedef __attribute__((ext_vector_type(4))) float floatx4;

#define MFMA16(a, b, c) __builtin_amdgcn_mfma_f32_16x16x32_bf16((a), (b), (c), 0, 0, 0)

__device__ __forceinline__ u16 f32_to_bf16(float f) {
  union { float f; unsigned int u; } c; c.f = f;
  unsigned int u = c.u + 0x7FFFu + ((c.u >> 16) & 1u);  // RNE
  return (u16)(u >> 16);
}
__device__ __forceinline__ float bf16_to_f32(u16 v) {
  union { unsigned int u; float f; } c; c.u = ((unsigned int)v) << 16;
  return c.f;
}
__device__ __forceinline__ float sigmoidf_(float x) {
  return 1.0f / (1.0f + __expf(-x));
}

// ---------------------------------------------------------------------------
// pack_B: Bp[c][k] = bf16( k<512 ? W[k][c] : U[k-512][c] ),  c in [0,1536), k in [0,1024)
// LDS-tiled transpose, 32x32 tiles, block (32,8).
// ---------------------------------------------------------------------------
__global__ void pack_B(const float* __restrict__ W, const float* __restrict__ U,
                       u16* __restrict__ Bp) {
  __shared__ float tile[32][33];
  const int kt = blockIdx.x * 32;   // k tile (0..1023)
  const int ct = blockIdx.y * 32;   // c tile (0..1535)
  const int tx = threadIdx.x;       // 0..31
  for (int i = threadIdx.y; i < 32; i += 8) {
    int k = kt + i, c = ct + tx;
    float v = (k < 512) ? W[(size_t)k * 1536 + c] : U[(size_t)(k - 512) * 1536 + c];
    tile[i][tx] = v;
  }
  __syncthreads();
  for (int i = threadIdx.y; i < 32; i += 8) {
    int c = ct + i, k = kt + tx;
    Bp[(size_t)c * 1024 + k] = f32_to_bf16(tile[tx][i]);
  }
}

// ---------------------------------------------------------------------------
// gru_step: one GRU timestep, fused GEMM + gates.
// Grid (64, 8): nb over 4096/64 rows, hb over 512/64 h-cols. 256 threads = 4 waves.
// Block tile: 64 n-rows x 64 h-cols x 3 gates (192 GEMM cols), K = 1024.
// Waves 2x2: wave (wy,wx) owns 32n x (3 gates x 32h).
// ---------------------------------------------------------------------------
__global__ __launch_bounds__(256, 2)
void gru_step(const float* __restrict__ x,
              const u16* __restrict__ Bp,
              const float* __restrict__ bias,   // [2][1536]
              const u16* __restrict__ h_in,
              u16* __restrict__ h_out,
              float* __restrict__ out,
              int t, int first, int last) {
  __shared__ alignas(16) u16 As[64][72];    // 64 rows x 64 k, +8 pad (16B-aligned rows)
  __shared__ alignas(16) u16 Bs[192][72];   // 192 cols x 64 k (transposed: k contiguous)

  const int tid = threadIdx.x;
  const int nb = blockIdx.x;
  const int hb = blockIdx.y;
  const int wid = tid >> 6;
  const int lane = tid & 63;
  const int wy = wid >> 1;       // n half (0..1)
  const int wx = wid & 1;        // h half (0..1)
  const int lrow = lane >> 4;    // quad (0..3)
  const int lcol = lane & 15;

  floatx4 acZ[2][2] = {{{0.f,0.f,0.f,0.f},{0.f,0.f,0.f,0.f}},{{0.f,0.f,0.f,0.f},{0.f,0.f,0.f,0.f}}};
  floatx4 acR[2][2] = {{{0.f,0.f,0.f,0.f},{0.f,0.f,0.f,0.f}},{{0.f,0.f,0.f,0.f},{0.f,0.f,0.f,0.f}}};
  floatx4 acX[2][2] = {{{0.f,0.f,0.f,0.f},{0.f,0.f,0.f,0.f}},{{0.f,0.f,0.f,0.f},{0.f,0.f,0.f,0.f}}};
  floatx4 acH[2][2] = {{{0.f,0.f,0.f,0.f},{0.f,0.f,0.f,0.f}},{{0.f,0.f,0.f,0.f},{0.f,0.f,0.f,0.f}}};

  const int mrow = tid >> 3;          // 0..31
  const int c8 = (tid & 7) * 8;       // k offset within tile

  // ---- Phase 0: K in [0,512) — x @ W (fp32 -> bf16 convert in staging) ----
  for (int kt = 0; kt < 8; ++kt) {
#pragma unroll
    for (int r2 = 0; r2 < 2; ++r2) {
      int m = r2 * 32 + mrow;
      int n = nb * 64 + m;
      size_t xrow = (size_t)((n >> 5) * 512 + t * 32 + (n & 31));
      const float* px = x + xrow * 512 + kt * 64 + c8;
      floatx4 va = *(const floatx4*)px;
      floatx4 vb = *(const floatx4*)(px + 4);
      u16x8 pk;
      pk[0] = f32_to_bf16(va[0]); pk[1] = f32_to_bf16(va[1]);
      pk[2] = f32_to_bf16(va[2]); pk[3] = f32_to_bf16(va[3]);
      pk[4] = f32_to_bf16(vb[0]); pk[5] = f32_to_bf16(vb[1]);
      pk[6] = f32_to_bf16(vb[2]); pk[7] = f32_to_bf16(vb[3]);
      *(u16x8*)&As[m][c8] = pk;
    }
#pragma unroll
    for (int i = 0; i < 6; ++i) {
      int ch = i * 256 + tid;
      int col = ch >> 3;               // 0..191
      int koff = (ch & 7) * 8;
      int gc = (col >> 6) * 512 + hb * 64 + (col & 63);
      *(u16x8*)&Bs[col][koff] =
          *(const u16x8*)(Bp + (size_t)gc * 1024 + (size_t)kt * 64 + koff);
    }
    __syncthreads();
#pragma unroll
    for (int kk = 0; kk < 2; ++kk) {
      short8 a0 = *(const short8*)&As[wy * 32 + lcol][kk * 32 + lrow * 8];
      short8 a1 = *(const short8*)&As[wy * 32 + 16 + lcol][kk * 32 + lrow * 8];
#pragma unroll
      for (int cih = 0; cih < 2; ++cih) {
        int cb = wx * 32 + cih * 16 + lcol;
        short8 bz = *(const short8*)&Bs[cb][kk * 32 + lrow * 8];
        short8 br = *(const short8*)&Bs[64 + cb][kk * 32 + lrow * 8];
        short8 bh = *(const short8*)&Bs[128 + cb][kk * 32 + lrow * 8];
        acZ[0][cih] = MFMA16(a0, bz, acZ[0][cih]);
        acZ[1][cih] = MFMA16(a1, bz, acZ[1][cih]);
        acR[0][cih] = MFMA16(a0, br, acR[0][cih]);
        acR[1][cih] = MFMA16(a1, br, acR[1][cih]);
        acX[0][cih] = MFMA16(a0, bh, acX[0][cih]);
        acX[1][cih] = MFMA16(a1, bh, acX[1][cih]);
      }
    }
    __syncthreads();
  }

  // ---- Phase 1: K in [512,1024) — h @ U (skipped on first step: h == 0) ----
  if (!first) {
    for (int kt = 0; kt < 8; ++kt) {
#pragma unroll
      for (int r2 = 0; r2 < 2; ++r2) {
        int m = r2 * 32 + mrow;
        int n = nb * 64 + m;
        *(u16x8*)&As[m][c8] =
            *(const u16x8*)(h_in + (size_t)n * 512 + (size_t)kt * 64 + c8);
      }
#pragma unroll
      for (int i = 0; i < 6; ++i) {
        int ch = i * 256 + tid;
        int col = ch >> 3;
        int koff = (ch & 7) * 8;
        int gc = (col >> 6) * 512 + hb * 64 + (col & 63);
        *(u16x8*)&Bs[col][koff] =
            *(const u16x8*)(Bp + (size_t)gc * 1024 + (size_t)(8 + kt) * 64 + koff);
      }
      __syncthreads();
#pragma unroll
      for (int kk = 0; kk < 2; ++kk) {
        short8 a0 = *(const short8*)&As[wy * 32 + lcol][kk * 32 + lrow * 8];
        short8 a1 = *(const short8*)&As[wy * 32 + 16 + lcol][kk * 32 + lrow * 8];
#pragma unroll
        for (int cih = 0; cih < 2; ++cih) {
          int cb = wx * 32 + cih * 16 + lcol;
          short8 bz = *(const short8*)&Bs[cb][kk * 32 + lrow * 8];
          short8 br = *(const short8*)&Bs[64 + cb][kk * 32 + lrow * 8];
          short8 bh = *(const short8*)&Bs[128 + cb][kk * 32 + lrow * 8];
          acZ[0][cih] = MFMA16(a0, bz, acZ[0][cih]);
          acZ[1][cih] = MFMA16(a1, bz, acZ[1][cih]);
          acR[0][cih] = MFMA16(a0, br, acR[0][cih]);
          acR[1][cih] = MFMA16(a1, br, acR[1][cih]);
          acH[0][cih] = MFMA16(a0, bh, acH[0][cih]);
          acH[1][cih] = MFMA16(a1, bh, acH[1][cih]);
        }
      }
      __syncthreads();
    }
  }

  // ---- Epilogue: gates. C/D layout: col = lane&15, row = (lane>>4)*4 + reg ----
  const float* b0 = bias;
  const float* b1 = bias + 1536;
#pragma unroll
  for (int cih = 0; cih < 2; ++cih) {
    int hg = hb * 64 + wx * 32 + cih * 16 + lcol;   // 0..511
    float b0z = b0[hg],        b1z = b1[hg];
    float b0r = b0[512 + hg],  b1r = b1[512 + hg];
    float b0h = b0[1024 + hg], b1h = b1[1024 + hg];
#pragma unroll
    for (int mi = 0; mi < 2; ++mi) {
      int nbase = nb * 64 + wy * 32 + mi * 16 + lrow * 4;
#pragma unroll
      for (int reg = 0; reg < 4; ++reg) {
        int n = nbase + reg;
        float z = sigmoidf_(acZ[mi][cih][reg] + b0z + b1z);
        float r = sigmoidf_(acR[mi][cih][reg] + b0r + b1r);
        float hh = acX[mi][cih][reg] + b0h + r * (acH[mi][cih][reg] + b1h);
        hh = fmaxf(hh, 0.0f);
        float hp = first ? 0.0f : bf16_to_f32(h_in[(size_t)n * 512 + hg]);
        float hn = z * hp + (1.0f - z) * hh;
        if (last) {
          out[(size_t)n * 512 + hg] = hn;   // h_final flat == (128,16384) layout
        } else {
          h_out[(size_t)n * 512 + hg] = f32_to_bf16(hn);
        }
      }
    }
  }
}

// ---------------------------------------------------------------------------
extern "C" void kernel_launch(void* const* d_in, const int* in_sizes, int n_in,
                              void* d_out, int out_size, void* d_ws, size_t ws_size,
                              hipStream_t stream) {
  const float* x = (const float*)d_in[0];    // (128,512,512)
  const float* W = (const float*)d_in[1];    // (512,1536)
  const float* U = (const float*)d_in[2];    // (512,1536)
  const float* bias = (const float*)d_in[3]; // (2,1536)
  float* out = (float*)d_out;                // (128,16384)

  u16* Bp = (u16*)d_ws;                      // 1536*1024 bf16 = 3 MB
  u16* h0 = Bp + (size_t)1536 * 1024;        // 4096*512 bf16 = 4 MB
  u16* h1 = h0 + (size_t)4096 * 512;         // 4 MB

  pack_B<<<dim3(32, 48), dim3(32, 8), 0, stream>>>(W, U, Bp);

  for (int t = 0; t < 16; ++t) {
    const u16* hin = (t & 1) ? h1 : h0;      // step 0 never reads h_in
    u16* hout = (t & 1) ? h0 : h1;
    gru_step<<<dim3(64, 8), 256, 0, stream>>>(
        x, Bp, bias, hin, hout, out, t, (t == 0) ? 1 : 0, (t == 15) ? 1 : 0);
  }
}